// Round 7
// baseline (98.969 us; speedup 1.0000x reference)
//
#include <hip/hip_runtime.h>

#define NB 32
#define NL 1024
#define NC 64
#define NO 64
constexpr float BN_EPS = 1e-5f;

// ws layout (float units):
//  [0..63]        scale
//  [64..127]      shift
//  [128..32895]   d  (B*L row degrees)
//  [32896..49279] bn partials (128 blocks x 64 ch, sum then sumsq)
//  [131072..]     Yt tiled bf16: [b][kt] 8KB tiles, swizzled   (4 MB)
//  [2097152..]    Abf tiled bf16: [b][mt][kt] 16KB tiles, swizzled (64 MB)
#define SCALE_OFF 0
#define SHIFT_OFF 64
#define D_OFF 128
#define PART_OFF 32896
#define YT_OFF 131072      // byte 512 KB (8KB aligned)
#define ABF_OFF 2097152    // byte 8 MB  (16KB aligned)

typedef short          s16x8 __attribute__((ext_vector_type(8)));
typedef unsigned short u16x4 __attribute__((ext_vector_type(4)));
typedef float          f32x16 __attribute__((ext_vector_type(16)));

__device__ inline unsigned short f2bf(float f) {
    union { float f; unsigned u; } v; v.f = f;
    unsigned u = v.u + 0x7FFFu + ((v.u >> 16) & 1u);   // round-to-nearest-even
    return (unsigned short)(u >> 16);
}

__device__ inline void gload16(const void* g, void* l) {
    __builtin_amdgcn_global_load_lds(
        (const __attribute__((address_space(1))) unsigned int*)g,
        (__attribute__((address_space(3))) unsigned int*)l, 16, 0, 0);
}

// ---- Kernel 1: fused  (blocks 0..2047: A degrees + bf16 tile convert, 16 rows/blk)
//                (blocks 2048..2175: BN partial sums over H) -------------------
__global__ __launch_bounds__(256) void degcvt_bn(
    const float* __restrict__ A, const float* __restrict__ H,
    float* __restrict__ ws, unsigned short* __restrict__ Abf) {
    const int t = threadIdx.x;
    if (blockIdx.x < 2048) {
        const int gr0 = blockIdx.x * 16;      // global node-row base (b*NL + i)
        const int b   = gr0 >> 10;
        const int i0  = gr0 & 1023;
        const int mt  = i0 >> 7;              // 128-row tile index
        const int r0  = i0 & 127;             // row within tile (multiple of 16)
        const int f   = t & 15;               // float4 slot within a K-tile
        const int rr  = t >> 4;               // 0..15 row within block
        const int r    = r0 + rr;
        const int grow = gr0 + rr;
        const float* Arow = A + (size_t)grow * NL;
        char* tbase = (char*)Abf + (size_t)(b * 8 + mt) * 16 * 16384;
        const int woff = (r * 128 + f * 8) ^ ((r & 7) << 4);
        float dsum = 0.f;
#pragma unroll
        for (int j = 0; j < 16; ++j) {        // j = K-tile index
            float4 v = *(const float4*)(Arow + j * 64 + f * 4);
            u16x4 h;
            h[0] = f2bf(v.x); h[1] = f2bf(v.y); h[2] = f2bf(v.z); h[3] = f2bf(v.w);
            *(u16x4*)(tbase + j * 16384 + woff) = h;
            dsum += v.x + v.y + v.z + v.w;
        }
#pragma unroll
        for (int m = 8; m; m >>= 1) dsum += __shfl_xor(dsum, m, 64);
        if (f == 0) ws[D_OFF + grow] = dsum;
    } else {
        __shared__ float ls[256], ls2[256];
        const int bb = blockIdx.x - 2048;     // 0..127
        const int c = t & 63, rg = t >> 6;    // rg 0..3
        float s = 0.f, s2 = 0.f;
        for (int r = bb * 4 + rg; r < NB * NL; r += 512) {
            float v = H[(size_t)r * NC + c];
            s += v; s2 += v * v;
        }
        ls[t] = s; ls2[t] = s2;
        __syncthreads();
        if (t < 64) {
            float a  = ls[c]  + ls[c + 64]  + ls[c + 128]  + ls[c + 192];
            float a2 = ls2[c] + ls2[c + 64] + ls2[c + 128] + ls2[c + 192];
            ws[PART_OFF + bb * 64 + c] = a;
            ws[PART_OFF + 128 * 64 + bb * 64 + c] = a2;
        }
    }
}

// ---- Kernel 2: finalize BN -> scale/shift ------------------------------------
__global__ void bn_finalize(const float* __restrict__ gamma,
                            const float* __restrict__ beta,
                            float* __restrict__ ws) {
    __shared__ float ls[256], ls2[256];
    int tid = threadIdx.x;
    int c = tid & 63, q = tid >> 6;
    const float* ps  = ws + PART_OFF;
    const float* ps2 = ws + PART_OFF + 128 * 64;
    float s = 0.f, s2 = 0.f;
    for (int p = q * 32; p < q * 32 + 32; ++p) {
        s  += ps[p * 64 + c];
        s2 += ps2[p * 64 + c];
    }
    ls[tid] = s; ls2[tid] = s2;
    __syncthreads();
    if (tid < 64) {
        float t  = ls[c]  + ls[c + 64]  + ls[c + 128]  + ls[c + 192];
        float t2 = ls2[c] + ls2[c + 64] + ls2[c + 128] + ls2[c + 192];
        const float n = (float)(NB * NL);
        float mean = t / n;
        float var  = t2 / n - mean * mean;
        float sc = gamma[c] * rsqrtf(var + BN_EPS);
        ws[SCALE_OFF + c] = sc;
        ws[SHIFT_OFF + c] = beta[c] - mean * sc;
    }
}

// ---- Kernel 3: X = Hn@W + b -> d_out;  Yt tiles = bf16(rsqrt(d)*X) swizzled --
__global__ __launch_bounds__(256) void linear_xy(
    const float* __restrict__ H, const float* __restrict__ Wm,
    const float* __restrict__ bias, const float* __restrict__ ws,
    float* __restrict__ X, unsigned short* __restrict__ Yt) {
    __shared__ float Wl[NC * NO];
    __shared__ float hnbuf[4][NC];
    __shared__ unsigned short ytile[64][66];
    const int b = blockIdx.x >> 4, ch = blockIdx.x & 15;   // ch = K-tile index
    const int r0g = b * NL + ch * 64;
    const int t = threadIdx.x, lane = t & 63, w = t >> 6;
    for (int k = t; k < NC * NO; k += 256) Wl[k] = Wm[k];
    const float sc = ws[SCALE_OFF + lane];
    const float sh = ws[SHIFT_OFF + lane];
    const float bo = bias[lane];
    const float* dbuf = ws + D_OFF;
    __syncthreads();
    for (int rr = w; rr < 64; rr += 4) {
        const int row = r0g + rr;
        float h = H[(size_t)row * NC + lane];
        hnbuf[w][lane] = h * sc + sh;
        float x = bo;
#pragma unroll
        for (int c4 = 0; c4 < NC; c4 += 4) {
            float4 h4 = *(const float4*)(&hnbuf[w][c4]);
            x += h4.x * Wl[(c4 + 0) * NO + lane];
            x += h4.y * Wl[(c4 + 1) * NO + lane];
            x += h4.z * Wl[(c4 + 2) * NO + lane];
            x += h4.w * Wl[(c4 + 3) * NO + lane];
        }
        X[(size_t)row * NO + lane] = x;
        ytile[rr][lane] = f2bf(x * rsqrtf(dbuf[row]));
    }
    __syncthreads();
    // tiled swizzled write: tile (b,ch), element (col, kk=lane)
    char* ybase = (char*)Yt + (size_t)(b * 16 + ch) * 8192;
#pragma unroll
    for (int i2 = 0; i2 < 16; ++i2) {
        const int col = i2 * 4 + w;
        *(unsigned short*)(ybase + ((col * 128 + lane * 2) ^ ((col & 7) << 4))) =
            ytile[lane][col];
    }
}

// ---- Kernel 4: out = leaky(X - sqrt(d_i) * (A @ Y))  [MFMA, gload_lds] -------
__global__ __launch_bounds__(512) void prop_mfma(
    const unsigned short* __restrict__ Abf, const unsigned short* __restrict__ Yt,
    const float* __restrict__ dbuf, float* __restrict__ XO) {

    __shared__ unsigned short Abuf[2][128 * 64];   // 2 x 16 KB (swizzled layout)
    __shared__ unsigned short Ybuf[2][64 * 64];    // 2 x 8 KB
    __shared__ float sdl[128];

    const int b  = blockIdx.x >> 3;
    const int mt = blockIdx.x & 7;
    const int i0 = mt * 128;
    const char* AbT = (const char*)Abf + (size_t)blockIdx.x * 16 * 16384;
    const char* YbT = (const char*)Yt  + (size_t)b * 16 * 8192;

    const int t    = threadIdx.x;
    const int lane = t & 63;
    const int w    = t >> 6;

    if (t < 128) sdl[t] = sqrtf(dbuf[b * NL + i0 + t]);

    const int wr0  = (w >> 1) * 32;
    const int wc0  = (w & 1) * 32;
    const int frow = wr0 + (lane & 31);
    const int fcol = wc0 + (lane & 31);
    const int khb  = (lane >> 5) * 16;

    f32x16 acc;
#pragma unroll
    for (int r = 0; r < 16; ++r) acc[r] = 0.f;

#define STAGE(bi, kt) do {                                                     \
        const char* asrc = AbT + (size_t)(kt) * 16384;                         \
        char* adst = (char*)Abuf[bi];                                          \
        gload16(asrc + w * 2048 + lane * 16,        adst + w * 2048 + lane * 16); \
        gload16(asrc + w * 2048 + 1024 + lane * 16, adst + w * 2048 + 1024 + lane * 16); \
        const char* ysrc = YbT + (size_t)(kt) * 8192;                          \
        gload16(ysrc + w * 1024 + lane * 16, (char*)Ybuf[bi] + w * 1024 + lane * 16); \
    } while (0)

    STAGE(0, 0);
    __syncthreads();

#pragma unroll 1
    for (int kti = 0; kti < 16; ++kti) {
        const int nxt = kti + 1;
        if (nxt < 16) STAGE(nxt & 1, nxt);      // prefetch next tile (async)
        const char* ab  = (const char*)Abuf[kti & 1];
        const char* yb2 = (const char*)Ybuf[kti & 1];
#pragma unroll
        for (int ks = 0; ks < 4; ++ks) {
            const int kb = ks * 32 + khb;
            s16x8 af = *(const s16x8*)(ab  + ((frow * 128 + kb) ^ ((frow & 7) << 4)));
            s16x8 bf = *(const s16x8*)(yb2 + ((fcol * 128 + kb) ^ ((fcol & 7) << 4)));
            acc = __builtin_amdgcn_mfma_f32_32x32x16_bf16(af, bf, acc, 0, 0, 0);
        }
        __syncthreads();                        // drains vmcnt: next tile resident
    }
#undef STAGE

    // epilogue: out = leaky(X - sqrt(d_i) * acc)
#pragma unroll
    for (int reg = 0; reg < 16; ++reg) {
        int row = (reg & 3) + 8 * (reg >> 2) + 4 * (lane >> 5);
        int i   = i0 + wr0 + row;
        int col = wc0 + (lane & 31);
        size_t idx = ((size_t)(b * NL + i)) * NO + col;
        float x = XO[idx];
        float v = x - sdl[wr0 + row] * acc[reg];
        XO[idx] = v > 0.f ? v : 0.01f * v;
    }
}

extern "C" void kernel_launch(void* const* d_in, const int* in_sizes, int n_in,
                              void* d_out, int out_size, void* d_ws, size_t ws_size,
                              hipStream_t stream) {
    const float* H     = (const float*)d_in[0];
    const float* A     = (const float*)d_in[1];
    const float* gamma = (const float*)d_in[2];
    const float* beta  = (const float*)d_in[3];
    const float* Wm    = (const float*)d_in[4];
    const float* bias  = (const float*)d_in[5];
    float* out = (float*)d_out;
    float* ws  = (float*)d_ws;
    unsigned short* Yt  = (unsigned short*)(ws + YT_OFF);
    unsigned short* Abf = (unsigned short*)(ws + ABF_OFF);

    degcvt_bn<<<2176, 256, 0, stream>>>(A, H, ws, Abf);
    bn_finalize<<<1, 256, 0, stream>>>(gamma, beta, ws);
    linear_xy<<<512, 256, 0, stream>>>(H, Wm, bias, ws, out, Yt);
    prop_mfma<<<256, 512, 0, stream>>>(Abf, Yt, ws + D_OFF, out);
}

// Round 8
// 94.858 us; speedup vs baseline: 1.0433x; 1.0433x over previous
//
#include <hip/hip_runtime.h>

#define NB 32
#define NL 1024
#define NC 64
#define NO 64
constexpr float BN_EPS = 1e-5f;

// ws layout (float units):
//  [0..63]        scale
//  [64..127]      shift
//  [128..32895]   d  (B*L row degrees)
//  [32896..49279] bn partials (128 blocks x 64 ch, sum then sumsq)
//  [131072..]     Yt tiled bf16: [b][kt] 8KB tiles, swizzled   (4 MB)
//  [2097152..]    Abf tiled bf16: [b][mt][kt] 16KB tiles, swizzled (64 MB)
#define SCALE_OFF 0
#define SHIFT_OFF 64
#define D_OFF 128
#define PART_OFF 32896
#define YT_OFF 131072      // byte 512 KB (8KB aligned)
#define ABF_OFF 2097152    // byte 8 MB  (16KB aligned)

typedef short          s16x8 __attribute__((ext_vector_type(8)));
typedef unsigned short u16x4 __attribute__((ext_vector_type(4)));
typedef float          f32x16 __attribute__((ext_vector_type(16)));
typedef float          f32x4  __attribute__((ext_vector_type(4)));

__device__ inline unsigned short f2bf(float f) {
    union { float f; unsigned u; } v; v.f = f;
    unsigned u = v.u + 0x7FFFu + ((v.u >> 16) & 1u);   // round-to-nearest-even
    return (unsigned short)(u >> 16);
}

__device__ inline void gload16(const void* g, void* l) {
    __builtin_amdgcn_global_load_lds(
        (const __attribute__((address_space(1))) unsigned int*)g,
        (__attribute__((address_space(3))) unsigned int*)l, 16, 0, 0);
}

// ---- Kernel 1: fused  (blocks 0..2047: A degrees + bf16 tile convert, 16 rows/blk)
//                (blocks 2048..2175: BN partial sums over H) -------------------
// Two-phase body: stage 16 float4 in registers (deep MLP), sched_barrier,
// then convert+store. Nontemporal A loads keep Abf/Yt resident in L3.
__global__ __launch_bounds__(256) void degcvt_bn(
    const float* __restrict__ A, const float* __restrict__ H,
    float* __restrict__ ws, unsigned short* __restrict__ Abf) {
    const int t = threadIdx.x;
    if (blockIdx.x < 2048) {
        const int gr0 = blockIdx.x * 16;      // global node-row base (b*NL + i)
        const int b   = gr0 >> 10;
        const int i0  = gr0 & 1023;
        const int mt  = i0 >> 7;              // 128-row tile index
        const int r0  = i0 & 127;             // row within tile (multiple of 16)
        const int f   = t & 15;               // float4 slot within a K-tile
        const int rr  = t >> 4;               // 0..15 row within block
        const int r    = r0 + rr;
        const int grow = gr0 + rr;
        const f32x4* Arow = (const f32x4*)(A + (size_t)grow * NL);
        char* tbase = (char*)Abf + (size_t)(b * 8 + mt) * 16 * 16384;
        const int woff = (r * 128 + f * 8) ^ ((r & 7) << 4);

        f32x4 v[16];
#pragma unroll
        for (int j = 0; j < 16; ++j)          // phase 1: 16 loads in flight
            v[j] = __builtin_nontemporal_load(Arow + j * 16 + f);
        __builtin_amdgcn_sched_barrier(0);    // pin: no store hoists above loads

        float dsum = 0.f;
#pragma unroll
        for (int j = 0; j < 16; ++j) {        // phase 2: convert + store
            u16x4 h;
            h[0] = f2bf(v[j].x); h[1] = f2bf(v[j].y);
            h[2] = f2bf(v[j].z); h[3] = f2bf(v[j].w);
            *(u16x4*)(tbase + j * 16384 + woff) = h;
            dsum += v[j].x + v[j].y + v[j].z + v[j].w;
        }
#pragma unroll
        for (int m = 8; m; m >>= 1) dsum += __shfl_xor(dsum, m, 64);
        if (f == 0) ws[D_OFF + grow] = dsum;
    } else {
        __shared__ float ls[256], ls2[256];
        const int bb = blockIdx.x - 2048;     // 0..127
        const int c = t & 63, rg = t >> 6;    // rg 0..3
        float s = 0.f, s2 = 0.f;
        for (int r = bb * 4 + rg; r < NB * NL; r += 512) {
            float v = H[(size_t)r * NC + c];
            s += v; s2 += v * v;
        }
        ls[t] = s; ls2[t] = s2;
        __syncthreads();
        if (t < 64) {
            float a  = ls[c]  + ls[c + 64]  + ls[c + 128]  + ls[c + 192];
            float a2 = ls2[c] + ls2[c + 64] + ls2[c + 128] + ls2[c + 192];
            ws[PART_OFF + bb * 64 + c] = a;
            ws[PART_OFF + 128 * 64 + bb * 64 + c] = a2;
        }
    }
}

// ---- Kernel 2: finalize BN -> scale/shift ------------------------------------
__global__ void bn_finalize(const float* __restrict__ gamma,
                            const float* __restrict__ beta,
                            float* __restrict__ ws) {
    __shared__ float ls[256], ls2[256];
    int tid = threadIdx.x;
    int c = tid & 63, q = tid >> 6;
    const float* ps  = ws + PART_OFF;
    const float* ps2 = ws + PART_OFF + 128 * 64;
    float s = 0.f, s2 = 0.f;
    for (int p = q * 32; p < q * 32 + 32; ++p) {
        s  += ps[p * 64 + c];
        s2 += ps2[p * 64 + c];
    }
    ls[tid] = s; ls2[tid] = s2;
    __syncthreads();
    if (tid < 64) {
        float t  = ls[c]  + ls[c + 64]  + ls[c + 128]  + ls[c + 192];
        float t2 = ls2[c] + ls2[c + 64] + ls2[c + 128] + ls2[c + 192];
        const float n = (float)(NB * NL);
        float mean = t / n;
        float var  = t2 / n - mean * mean;
        float sc = gamma[c] * rsqrtf(var + BN_EPS);
        ws[SCALE_OFF + c] = sc;
        ws[SHIFT_OFF + c] = beta[c] - mean * sc;
    }
}

// ---- Kernel 3: X = Hn@W + b -> d_out;  Yt tiles = bf16(rsqrt(d)*X) swizzled --
__global__ __launch_bounds__(256) void linear_xy(
    const float* __restrict__ H, const float* __restrict__ Wm,
    const float* __restrict__ bias, const float* __restrict__ ws,
    float* __restrict__ X, unsigned short* __restrict__ Yt) {
    __shared__ float Wl[NC * NO];
    __shared__ float hnbuf[4][NC];
    __shared__ unsigned short ytile[64][66];
    const int b = blockIdx.x >> 4, ch = blockIdx.x & 15;   // ch = K-tile index
    const int r0g = b * NL + ch * 64;
    const int t = threadIdx.x, lane = t & 63, w = t >> 6;
    for (int k = t; k < NC * NO; k += 256) Wl[k] = Wm[k];
    const float sc = ws[SCALE_OFF + lane];
    const float sh = ws[SHIFT_OFF + lane];
    const float bo = bias[lane];
    const float* dbuf = ws + D_OFF;
    __syncthreads();
    for (int rr = w; rr < 64; rr += 4) {
        const int row = r0g + rr;
        float h = H[(size_t)row * NC + lane];
        hnbuf[w][lane] = h * sc + sh;
        float x = bo;
#pragma unroll
        for (int c4 = 0; c4 < NC; c4 += 4) {
            float4 h4 = *(const float4*)(&hnbuf[w][c4]);
            x += h4.x * Wl[(c4 + 0) * NO + lane];
            x += h4.y * Wl[(c4 + 1) * NO + lane];
            x += h4.z * Wl[(c4 + 2) * NO + lane];
            x += h4.w * Wl[(c4 + 3) * NO + lane];
        }
        X[(size_t)row * NO + lane] = x;
        ytile[rr][lane] = f2bf(x * rsqrtf(dbuf[row]));
    }
    __syncthreads();
    // tiled swizzled write: tile (b,ch), element (col, kk=lane)
    char* ybase = (char*)Yt + (size_t)(b * 16 + ch) * 8192;
#pragma unroll
    for (int i2 = 0; i2 < 16; ++i2) {
        const int col = i2 * 4 + w;
        *(unsigned short*)(ybase + ((col * 128 + lane * 2) ^ ((col & 7) << 4))) =
            ytile[lane][col];
    }
}

// ---- Kernel 4: out = leaky(X - sqrt(d_i) * (A @ Y))  [MFMA, gload_lds] -------
__global__ __launch_bounds__(512) void prop_mfma(
    const unsigned short* __restrict__ Abf, const unsigned short* __restrict__ Yt,
    const float* __restrict__ dbuf, float* __restrict__ XO) {

    __shared__ unsigned short Abuf[2][128 * 64];   // 2 x 16 KB (swizzled layout)
    __shared__ unsigned short Ybuf[2][64 * 64];    // 2 x 8 KB
    __shared__ float sdl[128];

    const int b  = blockIdx.x >> 3;
    const int mt = blockIdx.x & 7;
    const int i0 = mt * 128;
    const char* AbT = (const char*)Abf + (size_t)blockIdx.x * 16 * 16384;
    const char* YbT = (const char*)Yt  + (size_t)b * 16 * 8192;

    const int t    = threadIdx.x;
    const int lane = t & 63;
    const int w    = t >> 6;

    if (t < 128) sdl[t] = sqrtf(dbuf[b * NL + i0 + t]);

    const int wr0  = (w >> 1) * 32;
    const int wc0  = (w & 1) * 32;
    const int frow = wr0 + (lane & 31);
    const int fcol = wc0 + (lane & 31);
    const int khb  = (lane >> 5) * 16;

    f32x16 acc;
#pragma unroll
    for (int r = 0; r < 16; ++r) acc[r] = 0.f;

#define STAGE(bi, kt) do {                                                     \
        const char* asrc = AbT + (size_t)(kt) * 16384;                         \
        char* adst = (char*)Abuf[bi];                                          \
        gload16(asrc + w * 2048 + lane * 16,        adst + w * 2048 + lane * 16); \
        gload16(asrc + w * 2048 + 1024 + lane * 16, adst + w * 2048 + 1024 + lane * 16); \
        const char* ysrc = YbT + (size_t)(kt) * 8192;                          \
        gload16(ysrc + w * 1024 + lane * 16, (char*)Ybuf[bi] + w * 1024 + lane * 16); \
    } while (0)

    STAGE(0, 0);
    __syncthreads();

#pragma unroll 1
    for (int kti = 0; kti < 16; ++kti) {
        const int nxt = kti + 1;
        if (nxt < 16) STAGE(nxt & 1, nxt);      // prefetch next tile (async)
        const char* ab  = (const char*)Abuf[kti & 1];
        const char* yb2 = (const char*)Ybuf[kti & 1];
#pragma unroll
        for (int ks = 0; ks < 4; ++ks) {
            const int kb = ks * 32 + khb;
            s16x8 af = *(const s16x8*)(ab  + ((frow * 128 + kb) ^ ((frow & 7) << 4)));
            s16x8 bf = *(const s16x8*)(yb2 + ((fcol * 128 + kb) ^ ((fcol & 7) << 4)));
            acc = __builtin_amdgcn_mfma_f32_32x32x16_bf16(af, bf, acc, 0, 0, 0);
        }
        __syncthreads();                        // drains vmcnt: next tile resident
    }
#undef STAGE

    // epilogue: out = leaky(X - sqrt(d_i) * acc)
#pragma unroll
    for (int reg = 0; reg < 16; ++reg) {
        int row = (reg & 3) + 8 * (reg >> 2) + 4 * (lane >> 5);
        int i   = i0 + wr0 + row;
        int col = wc0 + (lane & 31);
        size_t idx = ((size_t)(b * NL + i)) * NO + col;
        float x = XO[idx];
        float v = x - sdl[wr0 + row] * acc[reg];
        XO[idx] = v > 0.f ? v : 0.01f * v;
    }
}

extern "C" void kernel_launch(void* const* d_in, const int* in_sizes, int n_in,
                              void* d_out, int out_size, void* d_ws, size_t ws_size,
                              hipStream_t stream) {
    const float* H     = (const float*)d_in[0];
    const float* A     = (const float*)d_in[1];
    const float* gamma = (const float*)d_in[2];
    const float* beta  = (const float*)d_in[3];
    const float* Wm    = (const float*)d_in[4];
    const float* bias  = (const float*)d_in[5];
    float* out = (float*)d_out;
    float* ws  = (float*)d_ws;
    unsigned short* Yt  = (unsigned short*)(ws + YT_OFF);
    unsigned short* Abf = (unsigned short*)(ws + ABF_OFF);

    degcvt_bn<<<2176, 256, 0, stream>>>(A, H, ws, Abf);
    bn_finalize<<<1, 256, 0, stream>>>(gamma, beta, ws);
    linear_xy<<<512, 256, 0, stream>>>(H, Wm, bias, ws, out, Yt);
    prop_mfma<<<256, 512, 0, stream>>>(Abf, Yt, ws + D_OFF, out);
}